// Round 16
// baseline (53.391 us; speedup 1.0000x reference)
//
#include <hip/hip_runtime.h>

#define BB 4
#define CC 256
#define HH 50
#define WW 50
#define KK 1000
#define PP 7
#define NBIN 49              // 7*7
#define SCALE 0.0625f        // 1/16
#define CH 32                // channels per gather block (one 64-lane wave)
#define NQ (CH / 4)          // 8 channel-quads
#define ROWQ (WW * CC / 4)   // quad stride of one y row in NHWC = 3200
#define COLQ (CC / 4)        // quad stride of one x step = 64
#define WDS 52               // padded Wd rows (ny <= 50)

typedef float f32x4 __attribute__((ext_vector_type(4)));
typedef float f32x2 __attribute__((ext_vector_type(2)));

__device__ __forceinline__ unsigned short f32_to_bf(float f) {
    union { float f; unsigned int i; } c; c.f = f;
    const unsigned int r = c.i + 0x7FFFu + ((c.i >> 16) & 1u);   // round-nearest-even
    return (unsigned short)(r >> 16);
}
// u = (bf16 a | bf16 b<<16)  ->  {f32(a), f32(b)}
__device__ __forceinline__ f32x2 bfpair(unsigned int u) {
    union { unsigned int i; float f; } a, b;
    a.i = u << 16;
    b.i = u & 0xFFFF0000u;
    f32x2 r; r[0] = a.f; r[1] = b.f;
    return r;
}
__device__ __forceinline__ f32x2 fma2(f32x2 a, float b, f32x2 c) {
    return a * b + c;    // compiler emits v_pk_fma_f32
}

// --- per-axis sample computation, replicating reference boundary handling ---
__device__ __forceinline__ void axis_samples(float start, float bin, int p, float limit,
                                             int idx[4], float w[4]) {
#pragma unroll
    for (int i = 0; i < 2; ++i) {
        float s = (float)(p * 2 + i);
        float c = start + bin * (s + 0.5f) * 0.5f;   // /SR==2 exact as *0.5
        bool valid = (c > -1.0f) && (c < limit);
        c = fmaxf(c, 0.0f);
        float low = floorf(c);
        float high;
        if (low >= limit - 1.0f) { low = limit - 1.0f; c = low; high = low; }
        else high = low + 1.0f;
        float frac = c - low;
        idx[i * 2 + 0] = (int)low;
        idx[i * 2 + 1] = (int)high;
        w[i * 2 + 0] = valid ? (1.0f - frac) : 0.0f;
        w[i * 2 + 1] = valid ? frac : 0.0f;
    }
}

// --- NCHW f32 -> NHWC bf16 transpose: block per (b, y, 32-ch eighth) ---
__global__ __launch_bounds__(128) void xpose_kernel(const float* __restrict__ in,
                                                    unsigned short* __restrict__ out) {
    __shared__ float tile[32 * 51];           // 6528 B, stride-51 pad
    const int bid   = blockIdx.x;
    const int e     = bid & 7;                // 32-channel slice
    const int rem   = bid >> 3;
    const int y     = rem % HH;
    const int b     = rem / HH;
    const int t     = threadIdx.x;
    const int cbase = e * 32;
    for (int i = t; i < 32 * 25; i += 128) {
        const int c = i / 25, x2 = i % 25;
        const float2 v = *(const float2*)(in +
            (((size_t)(b * CC + cbase + c) * HH + y) * WW + 2 * x2));
        tile[c * 51 + 2 * x2]     = v.x;
        tile[c * 51 + 2 * x2 + 1] = v.y;
    }
    __syncthreads();
    unsigned short* ob = out + ((size_t)(b * HH + y) * WW) * CC + cbase;
    for (int j = t; j < WW * 8; j += 128) {
        const int x  = j >> 3;                // 8 channel-quads per x (this eighth)
        const int c0 = (j & 7) * 4;
        ushort4 v;
        v.x = f32_to_bf(tile[(c0 + 0) * 51 + x]);
        v.y = f32_to_bf(tile[(c0 + 1) * 51 + x]);
        v.z = f32_to_bf(tile[(c0 + 2) * 51 + x]);
        v.w = f32_to_bf(tile[(c0 + 3) * 51 + x]);
        *(ushort4*)(ob + (size_t)x * CC + c0) = v;   // keep in L2 for the gather
    }
}

// --- separable gather: ONE WAVE per (ROI, 32-ch eighth); 8000 blocks ---
// LDS cut to ~1.7 KB so the full grid is co-resident (31.25 <= 32 waves/CU).
// Direct global stores; block's output region is dense -> L2 write-combines.
__global__ __launch_bounds__(64, 8) void roialign_kernel(const uint2* __restrict__ fmap4,
                                                         const float* __restrict__ rois,
                                                         float* __restrict__ out) {
    __shared__ float s_wd[PP][WDS];                   // collapsed y-weights (x0.25)
    __shared__ int   s_xo[PP][4];                     // x tap offsets (quad units)
    __shared__ float s_xw[PP][4];

    const int bid = blockIdx.x;
    const int e   = bid & 7;             // channel eighth == XCD slot
    const int k   = bid >> 3;            // ROI
    const int t   = threadIdx.x;

    const int   b  = (int)rois[k * 5 + 0];
    const float x1 = rois[k * 5 + 1] * SCALE;
    const float y1 = rois[k * 5 + 2] * SCALE;
    const float x2 = rois[k * 5 + 3] * SCALE;
    const float y2 = rois[k * 5 + 4] * SCALE;
    const float bw = fmaxf(x2 - x1, 1.0f) * (1.0f / PP);
    const float bh = fmaxf(y2 - y1, 1.0f) * (1.0f / PP);

    // y bbox from the monotone extreme samples (s=0 lowest tap, s=13 highest)
    float c0f = fmaxf(y1 + bh * 0.25f, 0.0f);
    float l0 = floorf(c0f);
    if (l0 >= HH - 1.0f) l0 = HH - 1.0f;
    const int ylo = (int)l0;
    float c1f = fmaxf(y1 + bh * 6.75f, 0.0f);
    float l1 = floorf(c1f);
    float h1 = (l1 >= HH - 1.0f) ? (HH - 1.0f) : (l1 + 1.0f);
    const int ny = (int)h1 - ylo + 1;    // <= 50 always (indices clamped to [0,49])

    // table build inside one wave: lanes 0-6 own Wd rows, lanes 32-38 own x tables
    if (t < PP) {
        for (int y = 0; y < ny; ++y) s_wd[t][y] = 0.0f;
        int idx[4]; float w[4];
        axis_samples(y1, bh, t, (float)HH, idx, w);
#pragma unroll
        for (int j = 0; j < 4; ++j) s_wd[t][idx[j] - ylo] += 0.25f * w[j];
    } else if (t >= 32 && t < 32 + PP) {
        const int p = t - 32;
        int idx[4]; float w[4];
        axis_samples(x1, bw, p, (float)WW, idx, w);
#pragma unroll
        for (int j = 0; j < 4; ++j) { s_xo[p][j] = idx[j] * COLQ; s_xw[p][j] = w[j]; }
    }
    __syncthreads();   // one wave: compiles to waitcnt + cheap barrier

    const int pw  = t >> 3;          // 0..6 active, 7 idle
    const int chq = t & 7;
    if (pw < PP) {
        const int   xo0 = s_xo[pw][0], xo1 = s_xo[pw][1], xo2 = s_xo[pw][2], xo3 = s_xo[pw][3];
        const float w0 = s_xw[pw][0], w1 = s_xw[pw][1], w2 = s_xw[pw][2], w3 = s_xw[pw][3];
        f32x2 a0[PP] = {};           // channels c0,c0+1
        f32x2 a1[PP] = {};           // channels c0+2,c0+3
        const uint2* p = fmap4 + (size_t)b * (HH * ROWQ) + (size_t)ylo * ROWQ
                       + e * NQ + chq;
#pragma unroll 2
        for (int y = 0; y < ny; ++y, p += ROWQ) {
            const uint2 q0 = p[xo0], q1 = p[xo1], q2 = p[xo2], q3 = p[xo3];  // 8B/lane
            f32x2 txy = bfpair(q0.x) * w0;
            f32x2 tzw = bfpair(q0.y) * w0;
            txy = fma2(bfpair(q1.x), w1, txy);
            tzw = fma2(bfpair(q1.y), w1, tzw);
            txy = fma2(bfpair(q2.x), w2, txy);
            tzw = fma2(bfpair(q2.y), w2, tzw);
            txy = fma2(bfpair(q3.x), w3, txy);
            tzw = fma2(bfpair(q3.y), w3, tzw);
#pragma unroll
            for (int ph = 0; ph < PP; ++ph) {        // 14 pk_fma
                const float wy = s_wd[ph][y];        // uniform LDS broadcast
                a0[ph] = fma2(txy, wy, a0[ph]);
                a1[ph] = fma2(tzw, wy, a1[ph]);
            }
        }
        // direct stores: block region [e*32 .. e*32+31][49] is dense; L2 merges
        const int c0 = chq * 4;
        float* ob = out + (size_t)k * (CC * NBIN) + (size_t)e * (CH * NBIN) + c0 * NBIN;
#pragma unroll
        for (int ph = 0; ph < PP; ++ph) {
            const int bin = ph * PP + pw;
            ob[0 * NBIN + bin] = a0[ph][0];
            ob[1 * NBIN + bin] = a0[ph][1];
            ob[2 * NBIN + bin] = a1[ph][0];
            ob[3 * NBIN + bin] = a1[ph][1];
        }
    }
}

// --- fallback: direct NCHW f32 (only if ws too small) ---
__global__ __launch_bounds__(256) void roialign_nchw_kernel(const float* __restrict__ fmap,
                                                            const float* __restrict__ rois,
                                                            float* __restrict__ out) {
    __shared__ __align__(16) float sbuf[CC * NBIN];
    const int k = blockIdx.x;
    const int t = threadIdx.x;
    const int   b  = (int)rois[k * 5 + 0];
    const float x1 = rois[k * 5 + 1] * SCALE;
    const float y1 = rois[k * 5 + 2] * SCALE;
    const float x2 = rois[k * 5 + 3] * SCALE;
    const float y2 = rois[k * 5 + 4] * SCALE;
    const float bw = fmaxf(x2 - x1, 1.0f) * (1.0f / PP);
    const float bh = fmaxf(y2 - y1, 1.0f) * (1.0f / PP);
    for (int ph = 0; ph < PP; ++ph) {
        int ys[4]; float wy[4];
        axis_samples(y1, bh, ph, (float)HH, ys, wy);
        for (int pw = 0; pw < PP; ++pw) {
            int xs[4]; float wx[4];
            axis_samples(x1, bw, pw, (float)WW, xs, wx);
            float acc = 0.0f;
#pragma unroll
            for (int i = 0; i < 4; ++i)
#pragma unroll
                for (int j = 0; j < 4; ++j)
                    acc = fmaf(wy[i] * wx[j],
                               fmap[((size_t)(b * CC + t) * HH + ys[i]) * WW + xs[j]], acc);
            sbuf[t * NBIN + ph * PP + pw] = acc * 0.25f;
        }
    }
    __syncthreads();
    float4* o4 = (float4*)(out + (size_t)k * (CC * NBIN));
    const float4* s4 = (const float4*)sbuf;
    for (int i = t; i < (CC * NBIN) / 4; i += 256) o4[i] = s4[i];
}

extern "C" void kernel_launch(void* const* d_in, const int* in_sizes, int n_in,
                              void* d_out, int out_size, void* d_ws, size_t ws_size,
                              hipStream_t stream) {
    const float* input = (const float*)d_in[0];   // [B,C,H,W] f32
    const float* rois  = (const float*)d_in[1];   // [K,5] f32
    float* out = (float*)d_out;                   // [K,C,7,7] f32

    const size_t need = (size_t)BB * HH * WW * CC * sizeof(unsigned short);  // 5.12 MB
    if (ws_size >= need) {
        unsigned short* fmap = (unsigned short*)d_ws;
        xpose_kernel<<<BB * HH * 8, 128, 0, stream>>>(input, fmap);
        roialign_kernel<<<KK * 8, 64, 0, stream>>>((const uint2*)fmap, rois, out);
    } else {
        roialign_nchw_kernel<<<KK, 256, 0, stream>>>(input, rois, out);
    }
}

// Round 17
// 48.421 us; speedup vs baseline: 1.1026x; 1.1026x over previous
//
#include <hip/hip_runtime.h>

#define BB 4
#define CC 256
#define HH 50
#define WW 50
#define KK 1000
#define PP 7
#define NBIN 49              // 7*7
#define SCALE 0.0625f        // 1/16
#define CH 32                // channels per WAVE (each wave owns one eighth)
#define NQ (CH / 4)          // 8 channel-quads
#define ROWQ (WW * CC / 4)   // quad stride of one y row in NHWC = 3200
#define COLQ (CC / 4)        // quad stride of one x step = 64
#define WDS 52               // padded Wd rows (ny <= 50)

typedef float f32x4 __attribute__((ext_vector_type(4)));
typedef float f32x2 __attribute__((ext_vector_type(2)));

__device__ __forceinline__ unsigned short f32_to_bf(float f) {
    union { float f; unsigned int i; } c; c.f = f;
    const unsigned int r = c.i + 0x7FFFu + ((c.i >> 16) & 1u);   // round-nearest-even
    return (unsigned short)(r >> 16);
}
__device__ __forceinline__ float bf_to_f32(unsigned short u) {
    union { unsigned int i; float f; } c; c.i = (unsigned int)u << 16; return c.f;
}
// u = (bf16 a | bf16 b<<16)  ->  {f32(a), f32(b)}
__device__ __forceinline__ f32x2 bfpair(unsigned int u) {
    union { unsigned int i; float f; } a, b;
    a.i = u << 16;
    b.i = u & 0xFFFF0000u;
    f32x2 r; r[0] = a.f; r[1] = b.f;
    return r;
}
__device__ __forceinline__ f32x2 fma2(f32x2 a, float b, f32x2 c) {
    return a * b + c;    // compiler emits v_pk_fma_f32
}

// --- per-axis sample computation, replicating reference boundary handling ---
__device__ __forceinline__ void axis_samples(float start, float bin, int p, float limit,
                                             int idx[4], float w[4]) {
#pragma unroll
    for (int i = 0; i < 2; ++i) {
        float s = (float)(p * 2 + i);
        float c = start + bin * (s + 0.5f) * 0.5f;   // /SR==2 exact as *0.5
        bool valid = (c > -1.0f) && (c < limit);
        c = fmaxf(c, 0.0f);
        float low = floorf(c);
        float high;
        if (low >= limit - 1.0f) { low = limit - 1.0f; c = low; high = low; }
        else high = low + 1.0f;
        float frac = c - low;
        idx[i * 2 + 0] = (int)low;
        idx[i * 2 + 1] = (int)high;
        w[i * 2 + 0] = valid ? (1.0f - frac) : 0.0f;
        w[i * 2 + 1] = valid ? frac : 0.0f;
    }
}

// --- NCHW f32 -> NHWC bf16 transpose: block per (b, y, 32-ch eighth) ---
__global__ __launch_bounds__(128) void xpose_kernel(const float* __restrict__ in,
                                                    unsigned short* __restrict__ out) {
    __shared__ float tile[32 * 51];           // 6528 B, stride-51 pad
    const int bid   = blockIdx.x;
    const int e     = bid & 7;                // 32-channel slice
    const int rem   = bid >> 3;
    const int y     = rem % HH;
    const int b     = rem / HH;
    const int t     = threadIdx.x;
    const int cbase = e * 32;
    for (int i = t; i < 32 * 25; i += 128) {
        const int c = i / 25, x2 = i % 25;
        const float2 v = *(const float2*)(in +
            (((size_t)(b * CC + cbase + c) * HH + y) * WW + 2 * x2));
        tile[c * 51 + 2 * x2]     = v.x;
        tile[c * 51 + 2 * x2 + 1] = v.y;
    }
    __syncthreads();
    unsigned short* ob = out + ((size_t)(b * HH + y) * WW) * CC + cbase;
    for (int j = t; j < WW * 8; j += 128) {
        const int x  = j >> 3;                // 8 channel-quads per x (this eighth)
        const int c0 = (j & 7) * 4;
        ushort4 v;
        v.x = f32_to_bf(tile[(c0 + 0) * 51 + x]);
        v.y = f32_to_bf(tile[(c0 + 1) * 51 + x]);
        v.z = f32_to_bf(tile[(c0 + 2) * 51 + x]);
        v.w = f32_to_bf(tile[(c0 + 3) * 51 + x]);
        *(ushort4*)(ob + (size_t)x * CC + c0) = v;   // keep in L2 for the gather
    }
}

// --- separable gather: 2-wave block = (ROI, quarter); wave w owns eighth 2q+w ---
// WG-slot cap ~16/CU discovered in R16 -> 2 waves/WG gives 32 waves/CU; the
// whole 8000-wave grid is co-resident (31.25/CU). sout staged in bf16 keeps
// block LDS at 8 KB so LDS never binds; epilogue restores contiguous stores.
__global__ __launch_bounds__(128, 8) void roialign_kernel(const uint2* __restrict__ fmap4,
                                                          const float* __restrict__ rois,
                                                          float* __restrict__ out) {
    __shared__ unsigned short sout[2 * CH * NBIN];    // [c 0..63][49] bf16: 6272 B
    __shared__ float s_wd[PP][WDS];                   // collapsed y-weights (x0.25)
    __shared__ int   s_xo[PP][4];                     // x tap offsets (quad units)
    __shared__ float s_xw[PP][4];

    const int bid     = blockIdx.x;
    const int k       = bid >> 2;        // ROI
    const int quarter = bid & 3;         // channel quarter; wave picks eighth
    const int t       = threadIdx.x;
    const int wave    = t >> 6;
    const int lane    = t & 63;
    const int e       = quarter * 2 + wave;

    const int   b  = (int)rois[k * 5 + 0];
    const float x1 = rois[k * 5 + 1] * SCALE;
    const float y1 = rois[k * 5 + 2] * SCALE;
    const float x2 = rois[k * 5 + 3] * SCALE;
    const float y2 = rois[k * 5 + 4] * SCALE;
    const float bw = fmaxf(x2 - x1, 1.0f) * (1.0f / PP);
    const float bh = fmaxf(y2 - y1, 1.0f) * (1.0f / PP);

    // y bbox from the monotone extreme samples (s=0 lowest tap, s=13 highest)
    float c0f = fmaxf(y1 + bh * 0.25f, 0.0f);
    float l0 = floorf(c0f);
    if (l0 >= HH - 1.0f) l0 = HH - 1.0f;
    const int ylo = (int)l0;
    float c1f = fmaxf(y1 + bh * 6.75f, 0.0f);
    float l1 = floorf(c1f);
    float h1 = (l1 >= HH - 1.0f) ? (HH - 1.0f) : (l1 + 1.0f);
    const int ny = (int)h1 - ylo + 1;    // <= 50 always (indices clamped to [0,49])

    // table build: wave0 lanes 0-6 own Wd rows; wave1 lanes 0-6 own x tables
    if (t < PP) {
        for (int y = 0; y < ny; ++y) s_wd[t][y] = 0.0f;
        int idx[4]; float w[4];
        axis_samples(y1, bh, t, (float)HH, idx, w);
#pragma unroll
        for (int j = 0; j < 4; ++j) s_wd[t][idx[j] - ylo] += 0.25f * w[j];
    } else if (t >= 64 && t < 64 + PP) {
        const int p = t - 64;
        int idx[4]; float w[4];
        axis_samples(x1, bw, p, (float)WW, idx, w);
#pragma unroll
        for (int j = 0; j < 4; ++j) { s_xo[p][j] = idx[j] * COLQ; s_xw[p][j] = w[j]; }
    }
    __syncthreads();

    const int pw  = lane >> 3;       // 0..6 active, 7 idle
    const int chq = lane & 7;
    if (pw < PP) {
        const int   xo0 = s_xo[pw][0], xo1 = s_xo[pw][1], xo2 = s_xo[pw][2], xo3 = s_xo[pw][3];
        const float w0 = s_xw[pw][0], w1 = s_xw[pw][1], w2 = s_xw[pw][2], w3 = s_xw[pw][3];
        f32x2 a0[PP] = {};           // channels c0,c0+1
        f32x2 a1[PP] = {};           // channels c0+2,c0+3
        const uint2* p = fmap4 + (size_t)b * (HH * ROWQ) + (size_t)ylo * ROWQ
                       + e * NQ + chq;
#pragma unroll 2
        for (int y = 0; y < ny; ++y, p += ROWQ) {
            const uint2 q0 = p[xo0], q1 = p[xo1], q2 = p[xo2], q3 = p[xo3];  // 8B/lane
            f32x2 txy = bfpair(q0.x) * w0;
            f32x2 tzw = bfpair(q0.y) * w0;
            txy = fma2(bfpair(q1.x), w1, txy);
            tzw = fma2(bfpair(q1.y), w1, tzw);
            txy = fma2(bfpair(q2.x), w2, txy);
            tzw = fma2(bfpair(q2.y), w2, tzw);
            txy = fma2(bfpair(q3.x), w3, txy);
            tzw = fma2(bfpair(q3.y), w3, tzw);
#pragma unroll
            for (int ph = 0; ph < PP; ++ph) {        // 14 pk_fma
                const float wy = s_wd[ph][y];        // uniform LDS broadcast
                a0[ph] = fma2(txy, wy, a0[ph]);
                a1[ph] = fma2(tzw, wy, a1[ph]);
            }
        }
        const int c0 = wave * CH + chq * 4;          // this wave's 32-ch half of sout
#pragma unroll
        for (int ph = 0; ph < PP; ++ph) {            // <=2 lanes/bank: free
            const int bin = ph * PP + pw;
            sout[(c0 + 0) * NBIN + bin] = f32_to_bf(a0[ph][0]);
            sout[(c0 + 1) * NBIN + bin] = f32_to_bf(a0[ph][1]);
            sout[(c0 + 2) * NBIN + bin] = f32_to_bf(a1[ph][0]);
            sout[(c0 + 3) * NBIN + bin] = f32_to_bf(a1[ph][1]);
        }
    }
    __syncthreads();

    // epilogue: 12544 contiguous bytes per block (64ch x 49), nontemporal f32x4
    float* ob = out + (size_t)k * (CC * NBIN) + (size_t)quarter * (2 * CH * NBIN);
    for (int i = t; i < (2 * CH * NBIN) / 4; i += 128) {   // 784 quads
        const uint2 u = *(const uint2*)&sout[4 * i];       // 4 bf16, 8B aligned
        f32x4 v;
        v[0] = bf_to_f32((unsigned short)(u.x & 0xFFFFu));
        v[1] = bf_to_f32((unsigned short)(u.x >> 16));
        v[2] = bf_to_f32((unsigned short)(u.y & 0xFFFFu));
        v[3] = bf_to_f32((unsigned short)(u.y >> 16));
        __builtin_nontemporal_store(v, (f32x4*)ob + i);
    }
}

// --- fallback: direct NCHW f32 (only if ws too small) ---
__global__ __launch_bounds__(256) void roialign_nchw_kernel(const float* __restrict__ fmap,
                                                            const float* __restrict__ rois,
                                                            float* __restrict__ out) {
    __shared__ __align__(16) float sbuf[CC * NBIN];
    const int k = blockIdx.x;
    const int t = threadIdx.x;
    const int   b  = (int)rois[k * 5 + 0];
    const float x1 = rois[k * 5 + 1] * SCALE;
    const float y1 = rois[k * 5 + 2] * SCALE;
    const float x2 = rois[k * 5 + 3] * SCALE;
    const float y2 = rois[k * 5 + 4] * SCALE;
    const float bw = fmaxf(x2 - x1, 1.0f) * (1.0f / PP);
    const float bh = fmaxf(y2 - y1, 1.0f) * (1.0f / PP);
    for (int ph = 0; ph < PP; ++ph) {
        int ys[4]; float wy[4];
        axis_samples(y1, bh, ph, (float)HH, ys, wy);
        for (int pw = 0; pw < PP; ++pw) {
            int xs[4]; float wx[4];
            axis_samples(x1, bw, pw, (float)WW, xs, wx);
            float acc = 0.0f;
#pragma unroll
            for (int i = 0; i < 4; ++i)
#pragma unroll
                for (int j = 0; j < 4; ++j)
                    acc = fmaf(wy[i] * wx[j],
                               fmap[((size_t)(b * CC + t) * HH + ys[i]) * WW + xs[j]], acc);
            sbuf[t * NBIN + ph * PP + pw] = acc * 0.25f;
        }
    }
    __syncthreads();
    float4* o4 = (float4*)(out + (size_t)k * (CC * NBIN));
    const float4* s4 = (const float4*)sbuf;
    for (int i = t; i < (CC * NBIN) / 4; i += 256) o4[i] = s4[i];
}

extern "C" void kernel_launch(void* const* d_in, const int* in_sizes, int n_in,
                              void* d_out, int out_size, void* d_ws, size_t ws_size,
                              hipStream_t stream) {
    const float* input = (const float*)d_in[0];   // [B,C,H,W] f32
    const float* rois  = (const float*)d_in[1];   // [K,5] f32
    float* out = (float*)d_out;                   // [K,C,7,7] f32

    const size_t need = (size_t)BB * HH * WW * CC * sizeof(unsigned short);  // 5.12 MB
    if (ws_size >= need) {
        unsigned short* fmap = (unsigned short*)d_ws;
        xpose_kernel<<<BB * HH * 8, 128, 0, stream>>>(input, fmap);
        roialign_kernel<<<KK * 4, 128, 0, stream>>>((const uint2*)fmap, rois, out);
    } else {
        roialign_nchw_kernel<<<KK, 256, 0, stream>>>(input, rois, out);
    }
}

// Round 18
// 29.139 us; speedup vs baseline: 1.8323x; 1.6618x over previous
//
#include <hip/hip_runtime.h>

#define BB 4
#define CC 256
#define HH 50
#define WW 50
#define KK 1000
#define PP 7
#define NBIN 49              // 7*7
#define SCALE 0.0625f        // 1/16
#define CH 32                // channels per gather block (one 64-lane wave)
#define NQ (CH / 4)          // 8 channel-quads
#define ROWQ (WW * CC / 4)   // quad stride of one y row in NHWC = 3200
#define COLQ (CC / 4)        // quad stride of one x step = 64
#define WDS 52               // padded Wd rows (ny <= 50)

typedef float f32x4 __attribute__((ext_vector_type(4)));
typedef float f32x2 __attribute__((ext_vector_type(2)));

__device__ __forceinline__ unsigned short f32_to_bf(float f) {
    union { float f; unsigned int i; } c; c.f = f;
    const unsigned int r = c.i + 0x7FFFu + ((c.i >> 16) & 1u);   // round-nearest-even
    return (unsigned short)(r >> 16);
}
// u = (bf16 a | bf16 b<<16)  ->  {f32(a), f32(b)}
__device__ __forceinline__ f32x2 bfpair(unsigned int u) {
    union { unsigned int i; float f; } a, b;
    a.i = u << 16;
    b.i = u & 0xFFFF0000u;
    f32x2 r; r[0] = a.f; r[1] = b.f;
    return r;
}
__device__ __forceinline__ f32x2 fma2(f32x2 a, float b, f32x2 c) {
    return a * b + c;    // compiler emits v_pk_fma_f32
}

// --- per-axis sample computation, replicating reference boundary handling ---
__device__ __forceinline__ void axis_samples(float start, float bin, int p, float limit,
                                             int idx[4], float w[4]) {
#pragma unroll
    for (int i = 0; i < 2; ++i) {
        float s = (float)(p * 2 + i);
        float c = start + bin * (s + 0.5f) * 0.5f;   // /SR==2 exact as *0.5
        bool valid = (c > -1.0f) && (c < limit);
        c = fmaxf(c, 0.0f);
        float low = floorf(c);
        float high;
        if (low >= limit - 1.0f) { low = limit - 1.0f; c = low; high = low; }
        else high = low + 1.0f;
        float frac = c - low;
        idx[i * 2 + 0] = (int)low;
        idx[i * 2 + 1] = (int)high;
        w[i * 2 + 0] = valid ? (1.0f - frac) : 0.0f;
        w[i * 2 + 1] = valid ? frac : 0.0f;
    }
}

// --- NCHW f32 -> NHWC bf16 transpose: block per (b, y, 32-ch eighth) ---
__global__ __launch_bounds__(128) void xpose_kernel(const float* __restrict__ in,
                                                    unsigned short* __restrict__ out) {
    __shared__ float tile[32 * 51];           // 6528 B, stride-51 pad
    const int bid   = blockIdx.x;
    const int e     = bid & 7;                // 32-channel slice
    const int rem   = bid >> 3;
    const int y     = rem % HH;
    const int b     = rem / HH;
    const int t     = threadIdx.x;
    const int cbase = e * 32;
    for (int i = t; i < 32 * 25; i += 128) {
        const int c = i / 25, x2 = i % 25;
        const float2 v = *(const float2*)(in +
            (((size_t)(b * CC + cbase + c) * HH + y) * WW + 2 * x2));
        tile[c * 51 + 2 * x2]     = v.x;
        tile[c * 51 + 2 * x2 + 1] = v.y;
    }
    __syncthreads();
    unsigned short* ob = out + ((size_t)(b * HH + y) * WW) * CC + cbase;
    for (int j = t; j < WW * 8; j += 128) {
        const int x  = j >> 3;                // 8 channel-quads per x (this eighth)
        const int c0 = (j & 7) * 4;
        ushort4 v;
        v.x = f32_to_bf(tile[(c0 + 0) * 51 + x]);
        v.y = f32_to_bf(tile[(c0 + 1) * 51 + x]);
        v.z = f32_to_bf(tile[(c0 + 2) * 51 + x]);
        v.w = f32_to_bf(tile[(c0 + 3) * 51 + x]);
        *(ushort4*)(ob + (size_t)x * CC + c0) = v;   // keep in L2 for the gather
    }
}

// --- separable gather (R15 structure): ONE WAVE per (ROI, 32-ch eighth) ---
// Change vs R15: PLAIN cached stores in the epilogue (no nontemporal flag) so
// L2 write-combines full lines; R16/R17 counters showed nt => ~1.93x WRITE_SIZE.
__global__ __launch_bounds__(64, 8) void roialign_kernel(const uint2* __restrict__ fmap4,
                                                         const float* __restrict__ rois,
                                                         float* __restrict__ out) {
    __shared__ __align__(16) float sout[CH * NBIN];   // 6272 B, [c][49]
    __shared__ float s_wd[PP][WDS];                   // collapsed y-weights (x0.25)
    __shared__ int   s_xo[PP][4];                     // x tap offsets (quad units)
    __shared__ float s_xw[PP][4];

    const int bid = blockIdx.x;
    const int e   = bid & 7;             // channel eighth == XCD slot
    const int k   = bid >> 3;            // ROI
    const int t   = threadIdx.x;

    const int   b  = (int)rois[k * 5 + 0];
    const float x1 = rois[k * 5 + 1] * SCALE;
    const float y1 = rois[k * 5 + 2] * SCALE;
    const float x2 = rois[k * 5 + 3] * SCALE;
    const float y2 = rois[k * 5 + 4] * SCALE;
    const float bw = fmaxf(x2 - x1, 1.0f) * (1.0f / PP);
    const float bh = fmaxf(y2 - y1, 1.0f) * (1.0f / PP);

    // y bbox from the monotone extreme samples (s=0 lowest tap, s=13 highest)
    float c0f = fmaxf(y1 + bh * 0.25f, 0.0f);
    float l0 = floorf(c0f);
    if (l0 >= HH - 1.0f) l0 = HH - 1.0f;
    const int ylo = (int)l0;
    float c1f = fmaxf(y1 + bh * 6.75f, 0.0f);
    float l1 = floorf(c1f);
    float h1 = (l1 >= HH - 1.0f) ? (HH - 1.0f) : (l1 + 1.0f);
    const int ny = (int)h1 - ylo + 1;    // <= 50 always (indices clamped to [0,49])

    // table build inside one wave: lanes 0-6 own Wd rows, lanes 32-38 own x tables
    if (t < PP) {
        for (int y = 0; y < ny; ++y) s_wd[t][y] = 0.0f;
        int idx[4]; float w[4];
        axis_samples(y1, bh, t, (float)HH, idx, w);
#pragma unroll
        for (int j = 0; j < 4; ++j) s_wd[t][idx[j] - ylo] += 0.25f * w[j];
    } else if (t >= 32 && t < 32 + PP) {
        const int p = t - 32;
        int idx[4]; float w[4];
        axis_samples(x1, bw, p, (float)WW, idx, w);
#pragma unroll
        for (int j = 0; j < 4; ++j) { s_xo[p][j] = idx[j] * COLQ; s_xw[p][j] = w[j]; }
    }
    __syncthreads();   // one wave: compiles to s_waitcnt, no real barrier cost

    const int pw  = t >> 3;          // 0..6 active, 7 idle
    const int chq = t & 7;
    if (pw < PP) {
        const int   xo0 = s_xo[pw][0], xo1 = s_xo[pw][1], xo2 = s_xo[pw][2], xo3 = s_xo[pw][3];
        const float w0 = s_xw[pw][0], w1 = s_xw[pw][1], w2 = s_xw[pw][2], w3 = s_xw[pw][3];
        f32x2 a0[PP] = {};           // channels c0,c0+1
        f32x2 a1[PP] = {};           // channels c0+2,c0+3
        const uint2* p = fmap4 + (size_t)b * (HH * ROWQ) + (size_t)ylo * ROWQ
                       + e * NQ + chq;
#pragma unroll 2
        for (int y = 0; y < ny; ++y, p += ROWQ) {
            const uint2 q0 = p[xo0], q1 = p[xo1], q2 = p[xo2], q3 = p[xo3];  // 8B/lane
            f32x2 txy = bfpair(q0.x) * w0;
            f32x2 tzw = bfpair(q0.y) * w0;
            txy = fma2(bfpair(q1.x), w1, txy);
            tzw = fma2(bfpair(q1.y), w1, tzw);
            txy = fma2(bfpair(q2.x), w2, txy);
            tzw = fma2(bfpair(q2.y), w2, tzw);
            txy = fma2(bfpair(q3.x), w3, txy);
            tzw = fma2(bfpair(q3.y), w3, tzw);
#pragma unroll
            for (int ph = 0; ph < PP; ++ph) {        // 14 pk_fma
                const float wy = s_wd[ph][y];        // uniform LDS broadcast
                a0[ph] = fma2(txy, wy, a0[ph]);
                a1[ph] = fma2(tzw, wy, a1[ph]);
            }
        }
        const int c0 = chq * 4;
#pragma unroll
        for (int ph = 0; ph < PP; ++ph) {            // <=2 lanes/bank: free
            const int bin = ph * PP + pw;
            sout[(c0 + 0) * NBIN + bin] = a0[ph][0];
            sout[(c0 + 1) * NBIN + bin] = a0[ph][1];
            sout[(c0 + 2) * NBIN + bin] = a1[ph][0];
            sout[(c0 + 3) * NBIN + bin] = a1[ph][1];
        }
    }
    __syncthreads();

    // epilogue: 6272 contiguous bytes per block, PLAIN cached float4 stores
    f32x4* o4 = (f32x4*)(out + (size_t)k * (CC * NBIN) + (size_t)e * (CH * NBIN));
    const f32x4* s4 = (const f32x4*)sout;
    for (int i = t; i < CH * NBIN / 4; i += 64)
        o4[i] = s4[i];
}

// --- fallback: direct NCHW f32 (only if ws too small) ---
__global__ __launch_bounds__(256) void roialign_nchw_kernel(const float* __restrict__ fmap,
                                                            const float* __restrict__ rois,
                                                            float* __restrict__ out) {
    __shared__ __align__(16) float sbuf[CC * NBIN];
    const int k = blockIdx.x;
    const int t = threadIdx.x;
    const int   b  = (int)rois[k * 5 + 0];
    const float x1 = rois[k * 5 + 1] * SCALE;
    const float y1 = rois[k * 5 + 2] * SCALE;
    const float x2 = rois[k * 5 + 3] * SCALE;
    const float y2 = rois[k * 5 + 4] * SCALE;
    const float bw = fmaxf(x2 - x1, 1.0f) * (1.0f / PP);
    const float bh = fmaxf(y2 - y1, 1.0f) * (1.0f / PP);
    for (int ph = 0; ph < PP; ++ph) {
        int ys[4]; float wy[4];
        axis_samples(y1, bh, ph, (float)HH, ys, wy);
        for (int pw = 0; pw < PP; ++pw) {
            int xs[4]; float wx[4];
            axis_samples(x1, bw, pw, (float)WW, xs, wx);
            float acc = 0.0f;
#pragma unroll
            for (int i = 0; i < 4; ++i)
#pragma unroll
                for (int j = 0; j < 4; ++j)
                    acc = fmaf(wy[i] * wx[j],
                               fmap[((size_t)(b * CC + t) * HH + ys[i]) * WW + xs[j]], acc);
            sbuf[t * NBIN + ph * PP + pw] = acc * 0.25f;
        }
    }
    __syncthreads();
    float4* o4 = (float4*)(out + (size_t)k * (CC * NBIN));
    const float4* s4 = (const float4*)sbuf;
    for (int i = t; i < (CC * NBIN) / 4; i += 256) o4[i] = s4[i];
}

extern "C" void kernel_launch(void* const* d_in, const int* in_sizes, int n_in,
                              void* d_out, int out_size, void* d_ws, size_t ws_size,
                              hipStream_t stream) {
    const float* input = (const float*)d_in[0];   // [B,C,H,W] f32
    const float* rois  = (const float*)d_in[1];   // [K,5] f32
    float* out = (float*)d_out;                   // [K,C,7,7] f32

    const size_t need = (size_t)BB * HH * WW * CC * sizeof(unsigned short);  // 5.12 MB
    if (ws_size >= need) {
        unsigned short* fmap = (unsigned short*)d_ws;
        xpose_kernel<<<BB * HH * 8, 128, 0, stream>>>(input, fmap);
        roialign_kernel<<<KK * 8, 64, 0, stream>>>((const uint2*)fmap, rois, out);
    } else {
        roialign_nchw_kernel<<<KK, 256, 0, stream>>>(input, rois, out);
    }
}

// Round 19
// 29.076 us; speedup vs baseline: 1.8362x; 1.0021x over previous
//
#include <hip/hip_runtime.h>

#define BB 4
#define CC 256
#define HH 50
#define WW 50
#define KK 1000
#define PP 7
#define NBIN 49              // 7*7
#define SCALE 0.0625f        // 1/16
#define CH 32                // channels per gather block (one 64-lane wave)
#define NQ (CH / 4)          // 8 channel-quads
#define ROWQ (WW * CC / 4)   // quad stride of one y row in NHWC = 3200
#define COLQ (CC / 4)        // quad stride of one x step = 64
#define WDS 52               // padded Wd rows (ny <= 50)

typedef float f32x4 __attribute__((ext_vector_type(4)));
typedef float f32x2 __attribute__((ext_vector_type(2)));

__device__ __forceinline__ unsigned short f32_to_bf(float f) {
    union { float f; unsigned int i; } c; c.f = f;
    const unsigned int r = c.i + 0x7FFFu + ((c.i >> 16) & 1u);   // round-nearest-even
    return (unsigned short)(r >> 16);
}
// u = (bf16 a | bf16 b<<16)  ->  {f32(a), f32(b)}
__device__ __forceinline__ f32x2 bfpair(unsigned int u) {
    union { unsigned int i; float f; } a, b;
    a.i = u << 16;
    b.i = u & 0xFFFF0000u;
    f32x2 r; r[0] = a.f; r[1] = b.f;
    return r;
}
__device__ __forceinline__ f32x2 fma2(f32x2 a, float b, f32x2 c) {
    return a * b + c;    // compiler emits v_pk_fma_f32
}
// agent-scope store: writes THROUGH the (non-coherent) per-XCD L2 without
// allocating, merging into full lines at the Infinity Cache. Avoids both
// the plain-store L2 pollution (R18) and the nt partial-sector HBM RMW (R16/17).
__device__ __forceinline__ void store_sc0(f32x4* p, f32x4 v) {
    asm volatile("global_store_dwordx4 %0, %1, off sc0" :: "v"(p), "v"(v) : "memory");
}

// --- per-axis sample computation, replicating reference boundary handling ---
__device__ __forceinline__ void axis_samples(float start, float bin, int p, float limit,
                                             int idx[4], float w[4]) {
#pragma unroll
    for (int i = 0; i < 2; ++i) {
        float s = (float)(p * 2 + i);
        float c = start + bin * (s + 0.5f) * 0.5f;   // /SR==2 exact as *0.5
        bool valid = (c > -1.0f) && (c < limit);
        c = fmaxf(c, 0.0f);
        float low = floorf(c);
        float high;
        if (low >= limit - 1.0f) { low = limit - 1.0f; c = low; high = low; }
        else high = low + 1.0f;
        float frac = c - low;
        idx[i * 2 + 0] = (int)low;
        idx[i * 2 + 1] = (int)high;
        w[i * 2 + 0] = valid ? (1.0f - frac) : 0.0f;
        w[i * 2 + 1] = valid ? frac : 0.0f;
    }
}

// --- NCHW f32 -> NHWC bf16 transpose: block per (b, y, 32-ch eighth) ---
__global__ __launch_bounds__(128) void xpose_kernel(const float* __restrict__ in,
                                                    unsigned short* __restrict__ out) {
    __shared__ float tile[32 * 51];           // 6528 B, stride-51 pad
    const int bid   = blockIdx.x;
    const int e     = bid & 7;                // 32-channel slice
    const int rem   = bid >> 3;
    const int y     = rem % HH;
    const int b     = rem / HH;
    const int t     = threadIdx.x;
    const int cbase = e * 32;
    for (int i = t; i < 32 * 25; i += 128) {
        const int c = i / 25, x2 = i % 25;
        const float2 v = *(const float2*)(in +
            (((size_t)(b * CC + cbase + c) * HH + y) * WW + 2 * x2));
        tile[c * 51 + 2 * x2]     = v.x;
        tile[c * 51 + 2 * x2 + 1] = v.y;
    }
    __syncthreads();
    unsigned short* ob = out + ((size_t)(b * HH + y) * WW) * CC + cbase;
    for (int j = t; j < WW * 8; j += 128) {
        const int x  = j >> 3;                // 8 channel-quads per x (this eighth)
        const int c0 = (j & 7) * 4;
        ushort4 v;
        v.x = f32_to_bf(tile[(c0 + 0) * 51 + x]);
        v.y = f32_to_bf(tile[(c0 + 1) * 51 + x]);
        v.z = f32_to_bf(tile[(c0 + 2) * 51 + x]);
        v.w = f32_to_bf(tile[(c0 + 3) * 51 + x]);
        *(ushort4*)(ob + (size_t)x * CC + c0) = v;   // plain: stays in XCD-e L2
    }
}

// --- separable gather (R15 structure): ONE WAVE per (ROI, 32-ch eighth) ---
// Epilogue: sc0 (agent-scope) dwordx4 stores — the only change vs R15.
__global__ __launch_bounds__(64, 8) void roialign_kernel(const uint2* __restrict__ fmap4,
                                                         const float* __restrict__ rois,
                                                         float* __restrict__ out) {
    __shared__ __align__(16) float sout[CH * NBIN];   // 6272 B, [c][49]
    __shared__ float s_wd[PP][WDS];                   // collapsed y-weights (x0.25)
    __shared__ int   s_xo[PP][4];                     // x tap offsets (quad units)
    __shared__ float s_xw[PP][4];

    const int bid = blockIdx.x;
    const int e   = bid & 7;             // channel eighth == XCD slot
    const int k   = bid >> 3;            // ROI
    const int t   = threadIdx.x;

    const int   b  = (int)rois[k * 5 + 0];
    const float x1 = rois[k * 5 + 1] * SCALE;
    const float y1 = rois[k * 5 + 2] * SCALE;
    const float x2 = rois[k * 5 + 3] * SCALE;
    const float y2 = rois[k * 5 + 4] * SCALE;
    const float bw = fmaxf(x2 - x1, 1.0f) * (1.0f / PP);
    const float bh = fmaxf(y2 - y1, 1.0f) * (1.0f / PP);

    // y bbox from the monotone extreme samples (s=0 lowest tap, s=13 highest)
    float c0f = fmaxf(y1 + bh * 0.25f, 0.0f);
    float l0 = floorf(c0f);
    if (l0 >= HH - 1.0f) l0 = HH - 1.0f;
    const int ylo = (int)l0;
    float c1f = fmaxf(y1 + bh * 6.75f, 0.0f);
    float l1 = floorf(c1f);
    float h1 = (l1 >= HH - 1.0f) ? (HH - 1.0f) : (l1 + 1.0f);
    const int ny = (int)h1 - ylo + 1;    // <= 50 always (indices clamped to [0,49])

    // table build inside one wave: lanes 0-6 own Wd rows, lanes 32-38 own x tables
    if (t < PP) {
        for (int y = 0; y < ny; ++y) s_wd[t][y] = 0.0f;
        int idx[4]; float w[4];
        axis_samples(y1, bh, t, (float)HH, idx, w);
#pragma unroll
        for (int j = 0; j < 4; ++j) s_wd[t][idx[j] - ylo] += 0.25f * w[j];
    } else if (t >= 32 && t < 32 + PP) {
        const int p = t - 32;
        int idx[4]; float w[4];
        axis_samples(x1, bw, p, (float)WW, idx, w);
#pragma unroll
        for (int j = 0; j < 4; ++j) { s_xo[p][j] = idx[j] * COLQ; s_xw[p][j] = w[j]; }
    }
    __syncthreads();   // one wave: compiles to s_waitcnt, no real barrier cost

    const int pw  = t >> 3;          // 0..6 active, 7 idle
    const int chq = t & 7;
    if (pw < PP) {
        const int   xo0 = s_xo[pw][0], xo1 = s_xo[pw][1], xo2 = s_xo[pw][2], xo3 = s_xo[pw][3];
        const float w0 = s_xw[pw][0], w1 = s_xw[pw][1], w2 = s_xw[pw][2], w3 = s_xw[pw][3];
        f32x2 a0[PP] = {};           // channels c0,c0+1
        f32x2 a1[PP] = {};           // channels c0+2,c0+3
        const uint2* p = fmap4 + (size_t)b * (HH * ROWQ) + (size_t)ylo * ROWQ
                       + e * NQ + chq;
#pragma unroll 2
        for (int y = 0; y < ny; ++y, p += ROWQ) {
            const uint2 q0 = p[xo0], q1 = p[xo1], q2 = p[xo2], q3 = p[xo3];  // 8B/lane
            f32x2 txy = bfpair(q0.x) * w0;
            f32x2 tzw = bfpair(q0.y) * w0;
            txy = fma2(bfpair(q1.x), w1, txy);
            tzw = fma2(bfpair(q1.y), w1, tzw);
            txy = fma2(bfpair(q2.x), w2, txy);
            tzw = fma2(bfpair(q2.y), w2, tzw);
            txy = fma2(bfpair(q3.x), w3, txy);
            tzw = fma2(bfpair(q3.y), w3, tzw);
#pragma unroll
            for (int ph = 0; ph < PP; ++ph) {        // 14 pk_fma
                const float wy = s_wd[ph][y];        // uniform LDS broadcast
                a0[ph] = fma2(txy, wy, a0[ph]);
                a1[ph] = fma2(tzw, wy, a1[ph]);
            }
        }
        const int c0 = chq * 4;
#pragma unroll
        for (int ph = 0; ph < PP; ++ph) {            // <=2 lanes/bank: free
            const int bin = ph * PP + pw;
            sout[(c0 + 0) * NBIN + bin] = a0[ph][0];
            sout[(c0 + 1) * NBIN + bin] = a0[ph][1];
            sout[(c0 + 2) * NBIN + bin] = a1[ph][0];
            sout[(c0 + 3) * NBIN + bin] = a1[ph][1];
        }
    }
    __syncthreads();

    // epilogue: 6272 contiguous bytes per block, agent-scope (sc0) float4 stores
    f32x4* o4 = (f32x4*)(out + (size_t)k * (CC * NBIN) + (size_t)e * (CH * NBIN));
    const f32x4* s4 = (const f32x4*)sout;
    for (int i = t; i < CH * NBIN / 4; i += 64)
        store_sc0(&o4[i], s4[i]);
    asm volatile("s_waitcnt vmcnt(0)");
}

// --- fallback: direct NCHW f32 (only if ws too small) ---
__global__ __launch_bounds__(256) void roialign_nchw_kernel(const float* __restrict__ fmap,
                                                            const float* __restrict__ rois,
                                                            float* __restrict__ out) {
    __shared__ __align__(16) float sbuf[CC * NBIN];
    const int k = blockIdx.x;
    const int t = threadIdx.x;
    const int   b  = (int)rois[k * 5 + 0];
    const float x1 = rois[k * 5 + 1] * SCALE;
    const float y1 = rois[k * 5 + 2] * SCALE;
    const float x2 = rois[k * 5 + 3] * SCALE;
    const float y2 = rois[k * 5 + 4] * SCALE;
    const float bw = fmaxf(x2 - x1, 1.0f) * (1.0f / PP);
    const float bh = fmaxf(y2 - y1, 1.0f) * (1.0f / PP);
    for (int ph = 0; ph < PP; ++ph) {
        int ys[4]; float wy[4];
        axis_samples(y1, bh, ph, (float)HH, ys, wy);
        for (int pw = 0; pw < PP; ++pw) {
            int xs[4]; float wx[4];
            axis_samples(x1, bw, pw, (float)WW, xs, wx);
            float acc = 0.0f;
#pragma unroll
            for (int i = 0; i < 4; ++i)
#pragma unroll
                for (int j = 0; j < 4; ++j)
                    acc = fmaf(wy[i] * wx[j],
                               fmap[((size_t)(b * CC + t) * HH + ys[i]) * WW + xs[j]], acc);
            sbuf[t * NBIN + ph * PP + pw] = acc * 0.25f;
        }
    }
    __syncthreads();
    float4* o4 = (float4*)(out + (size_t)k * (CC * NBIN));
    const float4* s4 = (const float4*)sbuf;
    for (int i = t; i < (CC * NBIN) / 4; i += 256) o4[i] = s4[i];
}

extern "C" void kernel_launch(void* const* d_in, const int* in_sizes, int n_in,
                              void* d_out, int out_size, void* d_ws, size_t ws_size,
                              hipStream_t stream) {
    const float* input = (const float*)d_in[0];   // [B,C,H,W] f32
    const float* rois  = (const float*)d_in[1];   // [K,5] f32
    float* out = (float*)d_out;                   // [K,C,7,7] f32

    const size_t need = (size_t)BB * HH * WW * CC * sizeof(unsigned short);  // 5.12 MB
    if (ws_size >= need) {
        unsigned short* fmap = (unsigned short*)d_ws;
        xpose_kernel<<<BB * HH * 8, 128, 0, stream>>>(input, fmap);
        roialign_kernel<<<KK * 8, 64, 0, stream>>>((const uint2*)fmap, rois, out);
    } else {
        roialign_nchw_kernel<<<KK, 256, 0, stream>>>(input, rois, out);
    }
}